// Round 20
// baseline (8245.586 us; speedup 1.0000x reference)
//
#include <hip/hip_runtime.h>

#define BB 32
#define NN 16384
#define CC 64
#define NC 4096
#define T  512             // 8 waves/block = 2 waves/SIMD on one CU
#define SLOTS (NN / T)     // 32 points per thread

// ---------------------------------------------------------------------------
// FPS, one block per batch. Distance chain B1 = fma(dz,dz, fma(dx,dx, dy*dy))
// — bitwise-verified vs reference (R6, absmax 0; R19 ran this exact asm
// arithmetic and passed).
// R20: explicit AGPR homing for coords.
//   Established R11-R19: allocator caps this kernel at ~88 arch VGPRs under
//   every knob; 128-float state => ~100 values AGPR-homed; gfx950 VALU can't
//   source AGPRs, so every access pays v_accvgpr_read/write. R19 proved "v"
//   constraints just add copies around the asm (6.88ms). So: coords get "a"
//   constraints — only use is this asm -> homed in AGPR, one-time
//   accvgpr_write at init, and we pay EXACTLY one v_accvgpr_read per coord
//   per iter (the provable minimum). dist (RMW) + temps stay arch-VGPR
//   (~60 regs, under the 88 cap -> no copies).
//   11 insts/point: 3 accvgpr_read + 3 subrev + 1 mul + 2 fma + 1 min + 1 max.
// Kept (proven): DPP wave-max + LDS atomicMax on float bits [R14]; achievers
// rescan descending + atomicMin = numpy first-occurrence argmax [R7+];
// compact 12B-row centroid buffer in d_ws (L2-resident) [R12]; depth-4
// sentinel rotation, reset slot (it+2)&3 [R13+].
// ---------------------------------------------------------------------------

#define FOR32(M) M(0) M(1) M(2) M(3) M(4) M(5) M(6) M(7) \
                 M(8) M(9) M(10) M(11) M(12) M(13) M(14) M(15) \
                 M(16) M(17) M(18) M(19) M(20) M(21) M(22) M(23) \
                 M(24) M(25) M(26) M(27) M(28) M(29) M(30) M(31)

// One interleaved pair of points (a,b): 22 instructions.
#define PSTR(a, b) \
    "v_accvgpr_read_b32 %[t0], %[ax" #a "]\n\t" \
    "v_accvgpr_read_b32 %[t1], %[ay" #a "]\n\t" \
    "v_accvgpr_read_b32 %[t2], %[az" #a "]\n\t" \
    "v_accvgpr_read_b32 %[t4], %[ax" #b "]\n\t" \
    "v_accvgpr_read_b32 %[t5], %[ay" #b "]\n\t" \
    "v_accvgpr_read_b32 %[t6], %[az" #b "]\n\t" \
    "v_subrev_f32 %[t0], %[cx], %[t0]\n\t" \
    "v_subrev_f32 %[t1], %[cy], %[t1]\n\t" \
    "v_subrev_f32 %[t2], %[cz], %[t2]\n\t" \
    "v_subrev_f32 %[t4], %[cx], %[t4]\n\t" \
    "v_subrev_f32 %[t5], %[cy], %[t5]\n\t" \
    "v_subrev_f32 %[t6], %[cz], %[t6]\n\t" \
    "v_mul_f32 %[t3], %[t1], %[t1]\n\t" \
    "v_mul_f32 %[t7], %[t5], %[t5]\n\t" \
    "v_fma_f32 %[t3], %[t0], %[t0], %[t3]\n\t" \
    "v_fma_f32 %[t7], %[t4], %[t4], %[t7]\n\t" \
    "v_fma_f32 %[t3], %[t2], %[t2], %[t3]\n\t" \
    "v_fma_f32 %[t7], %[t6], %[t6], %[t7]\n\t" \
    "v_min_f32 %[d" #a "], %[d" #a "], %[t3]\n\t" \
    "v_min_f32 %[d" #b "], %[d" #b "], %[t7]\n\t" \
    "v_max_f32 %[aa], %[aa], %[d" #a "]\n\t" \
    "v_max_f32 %[ab], %[ab], %[d" #b "]\n\t"

#define DOUT(i) , [d##i] "+v"(dist[i])
#define AIN(i)  , [ax##i] "a"(px[i]), [ay##i] "a"(py[i]), [az##i] "a"(pz[i])

template <int CTRL>
__device__ __forceinline__ float dpp_max(float x) {
    const int yi = __builtin_amdgcn_update_dpp(0, __float_as_int(x),
                                               CTRL, 0xf, 0xf, true);
    return fmaxf(x, __int_as_float(yi));
}

__device__ __forceinline__ float wave_max_dpp(float x) {
    x = dpp_max<0x111>(x);   // row_shr:1
    x = dpp_max<0x112>(x);   // row_shr:2
    x = dpp_max<0x114>(x);   // row_shr:4
    x = dpp_max<0x118>(x);   // row_shr:8
    x = dpp_max<0x142>(x);   // row_bcast:15
    x = dpp_max<0x143>(x);   // row_bcast:31
    return x;                // valid in lane 63
}

// cb0/cstride: centroid re-read source (compact: stride 3; fallback: 64).
__global__ __launch_bounds__(T)
__attribute__((amdgpu_waves_per_eu(2, 2)))
void fps_kernel(const float* __restrict__ in,
                float* __restrict__ out,
                const float* __restrict__ cb0,
                int cstride) {
#pragma clang fp contract(off)
    const int b    = blockIdx.x;
    const int t    = threadIdx.x;
    const int lane = t & 63;

    __shared__ unsigned s_gbits4[4];
    __shared__ int      s_far4[4];

    const float* base = in + (size_t)b * NN * CC;
    const float* cb   = cb0 + (size_t)b * NN * cstride;

    float px[SLOTS], py[SLOTS], pz[SLOTS], dist[SLOTS];
#pragma unroll
    for (int j = 0; j < SLOTS; ++j) {
        const int i = j * T + t;
        const float4 v = *reinterpret_cast<const float4*>(base + (size_t)i * CC);
        px[j] = v.x; py[j] = v.y; pz[j] = v.z;
        dist[j] = 1e10f;
    }
    if (t < 4) { s_far4[t] = 0x7fffffff; s_gbits4[t] = 0u; }

    float cx = base[0], cy = base[1], cz = base[2];   // point 0
    int   far = 0;
    __syncthreads();

    int* idx_out = reinterpret_cast<int*>(out);

    for (int it = 0; it < NC; ++it) {
        if (t == 0) idx_out[((size_t)b * NC + it) * CC] = far;
        if (it == NC - 1) break;

        // uniform centroid -> SGPRs (legal in src0 of the VOP2s in the asm)
        const float cxs = __uint_as_float(__builtin_amdgcn_readfirstlane(__float_as_uint(cx)));
        const float cys = __uint_as_float(__builtin_amdgcn_readfirstlane(__float_as_uint(cy)));
        const float czs = __uint_as_float(__builtin_amdgcn_readfirstlane(__float_as_uint(cz)));

        // ---- dist update (chain B1, bitwise-exact): ONE asm block;
        //      coords live in AGPRs ("a"), exactly 1 accvgpr_read per use ----
        float accA = -1.0f, accB = -1.0f;
        float q0, q1, q2, q3, q4, q5, q6, q7;
        asm(PSTR(0, 1)   PSTR(2, 3)   PSTR(4, 5)   PSTR(6, 7)
            PSTR(8, 9)   PSTR(10, 11) PSTR(12, 13) PSTR(14, 15)
            PSTR(16, 17) PSTR(18, 19) PSTR(20, 21) PSTR(22, 23)
            PSTR(24, 25) PSTR(26, 27) PSTR(28, 29) PSTR(30, 31)
            : [aa] "+v"(accA), [ab] "+v"(accB),
              [t0] "=&v"(q0), [t1] "=&v"(q1), [t2] "=&v"(q2), [t3] "=&v"(q3),
              [t4] "=&v"(q4), [t5] "=&v"(q5), [t6] "=&v"(q6), [t7] "=&v"(q7)
              FOR32(DOUT)
            : [cx] "s"(cxs), [cy] "s"(cys), [cz] "s"(czs)
              FOR32(AIN));
        const float lv = fmaxf(accA, accB);

        // ---- wave64 max via DPP; lane 63 -> LDS atomicMax on bits ----
        const float wv = wave_max_dpp(lv);
        if (lane == 63)
            atomicMax(&s_gbits4[it & 3], __float_as_uint(wv));

        if (t == 0) {              // reset slot used 2 iters ahead (barrier-safe)
            s_far4[(it + 2) & 3]   = 0x7fffffff;
            s_gbits4[(it + 2) & 3] = 0u;
        }
        __syncthreads();                                  // A

        const float gm = __uint_as_float(s_gbits4[it & 3]);

        // ---- achievers: first local index (descending), atomicMin ----
        if (lv == gm) {
            int myi = 0x7fffffff;
#pragma unroll
            for (int j = SLOTS - 1; j >= 0; --j)
                myi = (dist[j] == gm) ? (j * T + t) : myi;
            atomicMin(&s_far4[it & 3], myi);
        }
        __syncthreads();                                  // B

        far = s_far4[it & 3];

        // ---- centroid reload (compact L2-resident buffer, or strided) ----
        cx = cb[(size_t)far * cstride + 0];
        cy = cb[(size_t)far * cstride + 1];
        cz = cb[(size_t)far * cstride + 2];
    }
}

// ---------------------------------------------------------------------------
// One-time xyz compaction: in[b][i][0..2] -> cpts[b][i*3+{0,1,2}] (12B rows).
// ---------------------------------------------------------------------------
__global__ __launch_bounds__(256) void compact_kernel(const float* __restrict__ in,
                                                      float* __restrict__ cpts) {
    const int gid = blockIdx.x * blockDim.x + threadIdx.x;   // one point each
    const int b   = gid >> 14;                               // NN == 16384
    const int i   = gid & (NN - 1);
    const float* src = in + ((size_t)b * NN + i) * CC;
    float* dst = cpts + ((size_t)b * NN + i) * 3;
    dst[0] = src[0];
    dst[1] = src[1];
    dst[2] = src[2];
}

// ---------------------------------------------------------------------------
// Gather kernel: one wave64 per output row (64 channels).
// ---------------------------------------------------------------------------
__global__ __launch_bounds__(256) void gather_kernel(const float* __restrict__ in,
                                                     float* out) {
    const int gid  = blockIdx.x * blockDim.x + threadIdx.x;
    const int row  = gid >> 6;     // 0 .. B*NC-1
    const int lane = gid & 63;     // channel
    const int b = row >> 12;       // NC == 4096
    const int idx = reinterpret_cast<const int*>(out)[(size_t)row * CC];
    const float v = in[((size_t)b * NN + idx) * CC + lane];
    out[(size_t)row * CC + lane] = v;
}

extern "C" void kernel_launch(void* const* d_in, const int* in_sizes, int n_in,
                              void* d_out, int out_size, void* d_ws, size_t ws_size,
                              hipStream_t stream) {
    const float* in = (const float*)d_in[0];
    float* out = (float*)d_out;

    const size_t ws_need = (size_t)BB * NN * 3 * sizeof(float);   // 6 MB
    if (ws_size >= ws_need) {
        float* cpts = (float*)d_ws;
        compact_kernel<<<(BB * NN) / 256, 256, 0, stream>>>(in, cpts);
        fps_kernel<<<BB, T, 0, stream>>>(in, out, cpts, 3);
    } else {
        fps_kernel<<<BB, T, 0, stream>>>(in, out, in, CC);
    }

    const int total = BB * NC * CC;          // 8,388,608
    gather_kernel<<<total / 256, 256, 0, stream>>>(in, out);
}

// Round 21
// 5469.669 us; speedup vs baseline: 1.5075x; 1.5075x over previous
//
#include <hip/hip_runtime.h>

#define BB 32
#define NN 16384
#define CC 64
#define NC 4096
#define T  512             // 8 waves/block = 2 waves/SIMD on one CU
#define SLOTS (NN / T)     // 32 points per thread

// ---------------------------------------------------------------------------
// FPS, one block per batch. Distance chain B1 = fma(dz,dz, fma(dx,dx, dy*dy))
// — bitwise-verified vs reference (R6, absmax 0).
// R21 = R17 (best, 5.33ms) with two changes:
//  1. coord init reads the COMPACT 12B-row buffer (bit-exact copy of xyz):
//     one-time HBM init 32MB->6MB, and if the allocator has been remat-
//     reloading loop-invariant coords from cache, the stream is 5x smaller.
//  2. single-barrier argmax: per-wave (value DPP-chain -> lane63; broadcast;
//     achievers rescan descending for first local slot; complement-index
//     DPP-max chain -> lane63) then ONE u64 LDS atomicMax per wave:
//     hi32 = dist bits (>=0 -> bit order == float order),
//     lo32 = 0x7FFFFFFF - idx (ties -> smallest index = numpy argmax).
//     Deletes barrier B + the atomicMin round. Depth-4 slot rotation kept
//     (reset slot (it+2)&3 is >=2 barriers from its uses).
// R15-R20 lesson: every hand-forced register-homing variant (asm "v", asm
// "a", LDS dist, waves_per_eu, named scalars) loses to the compiler's own
// schedule. This round keeps the compiler's loop verbatim.
// ---------------------------------------------------------------------------

template <int CTRL>
__device__ __forceinline__ float dpp_max_f(float x) {
    const int yi = __builtin_amdgcn_update_dpp(0, __float_as_int(x),
                                               CTRL, 0xf, 0xf, true);
    return fmaxf(x, __int_as_float(yi));
}
template <int CTRL>
__device__ __forceinline__ int dpp_max_i(int x) {
    const int y = __builtin_amdgcn_update_dpp(0, x, CTRL, 0xf, 0xf, true);
    return (x > y) ? x : y;
}

__device__ __forceinline__ float wave_max_f(float x) {
    x = dpp_max_f<0x111>(x);   // row_shr:1
    x = dpp_max_f<0x112>(x);   // row_shr:2
    x = dpp_max_f<0x114>(x);   // row_shr:4
    x = dpp_max_f<0x118>(x);   // row_shr:8
    x = dpp_max_f<0x142>(x);   // row_bcast:15
    x = dpp_max_f<0x143>(x);   // row_bcast:31
    return x;                  // full max valid in lane 63
}
__device__ __forceinline__ int wave_max_i(int x) {
    x = dpp_max_i<0x111>(x);
    x = dpp_max_i<0x112>(x);
    x = dpp_max_i<0x114>(x);
    x = dpp_max_i<0x118>(x);
    x = dpp_max_i<0x142>(x);
    x = dpp_max_i<0x143>(x);
    return x;                  // full max valid in lane 63
}

// pinit/istride: coord init source. cb/cstride: centroid re-read source.
__global__ __launch_bounds__(T)
__attribute__((amdgpu_waves_per_eu(2, 2)))
void fps_kernel(float* __restrict__ out,
                const float* __restrict__ pinit, int istride,
                const float* __restrict__ cb0,  int cstride) {
#pragma clang fp contract(off)
    const int b    = blockIdx.x;
    const int t    = threadIdx.x;
    const int lane = t & 63;

    __shared__ unsigned long long s_pk4[4];

    const float* pb = pinit + (size_t)b * NN * istride;
    const float* cb = cb0  + (size_t)b * NN * cstride;

    float px[SLOTS], py[SLOTS], pz[SLOTS], dist[SLOTS];
#pragma unroll
    for (int j = 0; j < SLOTS; ++j) {
        const size_t r = (size_t)(j * T + t) * istride;
        px[j] = pb[r + 0];
        py[j] = pb[r + 1];
        pz[j] = pb[r + 2];
        dist[j] = 1e10f;
    }
    // Coords non-rematerializable (no reload-spill to global).
#pragma unroll
    for (int j = 0; j < SLOTS; ++j) {
        asm("" : "+v"(px[j]), "+v"(py[j]), "+v"(pz[j]));
    }
    if (t < 4) s_pk4[t] = 0ull;

    float cx = cb[0], cy = cb[1], cz = cb[2];   // point 0
    int   far = 0;
    __syncthreads();

    int* idx_out = reinterpret_cast<int*>(out);

    for (int it = 0; it < NC; ++it) {
        if (t == 0) idx_out[((size_t)b * NC + it) * CC] = far;
        if (it == NC - 1) break;

        // ---- dist update (chain B1, bitwise-exact); 4 independent maxes ----
        float a0 = -1.0f, a1 = -1.0f, a2 = -1.0f, a3 = -1.0f;
#pragma unroll
        for (int j = 0; j < SLOTS; j += 4) {
            {
                const float dx = px[j] - cx, dy = py[j] - cy, dz = pz[j] - cz;
                const float d  = fmaf(dz, dz, fmaf(dx, dx, dy * dy));
                const float nd = fminf(dist[j], d);
                dist[j] = nd; a0 = fmaxf(a0, nd);
            }
            {
                const float dx = px[j+1] - cx, dy = py[j+1] - cy, dz = pz[j+1] - cz;
                const float d  = fmaf(dz, dz, fmaf(dx, dx, dy * dy));
                const float nd = fminf(dist[j+1], d);
                dist[j+1] = nd; a1 = fmaxf(a1, nd);
            }
            {
                const float dx = px[j+2] - cx, dy = py[j+2] - cy, dz = pz[j+2] - cz;
                const float d  = fmaf(dz, dz, fmaf(dx, dx, dy * dy));
                const float nd = fminf(dist[j+2], d);
                dist[j+2] = nd; a2 = fmaxf(a2, nd);
            }
            {
                const float dx = px[j+3] - cx, dy = py[j+3] - cy, dz = pz[j+3] - cz;
                const float d  = fmaf(dz, dz, fmaf(dx, dx, dy * dy));
                const float nd = fminf(dist[j+3], d);
                dist[j+3] = nd; a3 = fmaxf(a3, nd);
            }
        }
        const float lv = fmaxf(fmaxf(a0, a1), fmaxf(a2, a3));

        // ---- per-wave fused (value, index) reduce ----
        const float wv  = wave_max_f(lv);                         // lane63 full
        const int   wvb = __builtin_amdgcn_readlane(__float_as_int(wv), 63);
        int myc = 0;                                              // 0 = neutral
        if (__float_as_int(lv) == wvb) {                          // wave achievers
            const float gv = __int_as_float(wvb);
            int myi = 0x7fffffff;
#pragma unroll
            for (int j = SLOTS - 1; j >= 0; --j)                  // first slot kept
                myi = (dist[j] == gv) ? (j * T + t) : myi;
            myc = 0x7fffffff - myi;                               // complement
        }
        const int wc = wave_max_i(myc);                           // lane63 full

        if (lane == 63)
            atomicMax(&s_pk4[it & 3],
                      ((unsigned long long)(unsigned)wvb << 32) | (unsigned)wc);
        if (t == 0) s_pk4[(it + 2) & 3] = 0ull;                   // rotate reset
        __syncthreads();                                          // ONE barrier

        const unsigned long long pk = s_pk4[it & 3];
        far = 0x7fffffff - (int)(unsigned)(pk & 0xffffffffu);

        // ---- centroid reload (compact L2-resident buffer, or strided) ----
        cx = cb[(size_t)far * cstride + 0];
        cy = cb[(size_t)far * cstride + 1];
        cz = cb[(size_t)far * cstride + 2];
    }
}

// ---------------------------------------------------------------------------
// One-time xyz compaction: in[b][i][0..2] -> cpts[b][i*3+{0,1,2}] (12B rows).
// ---------------------------------------------------------------------------
__global__ __launch_bounds__(256) void compact_kernel(const float* __restrict__ in,
                                                      float* __restrict__ cpts) {
    const int gid = blockIdx.x * blockDim.x + threadIdx.x;   // one point each
    const int b   = gid >> 14;                               // NN == 16384
    const int i   = gid & (NN - 1);
    const float* src = in + ((size_t)b * NN + i) * CC;
    float* dst = cpts + ((size_t)b * NN + i) * 3;
    dst[0] = src[0];
    dst[1] = src[1];
    dst[2] = src[2];
}

// ---------------------------------------------------------------------------
// Gather kernel: one wave64 per output row (64 channels).
// ---------------------------------------------------------------------------
__global__ __launch_bounds__(256) void gather_kernel(const float* __restrict__ in,
                                                     float* out) {
    const int gid  = blockIdx.x * blockDim.x + threadIdx.x;
    const int row  = gid >> 6;     // 0 .. B*NC-1
    const int lane = gid & 63;     // channel
    const int b = row >> 12;       // NC == 4096
    const int idx = reinterpret_cast<const int*>(out)[(size_t)row * CC];
    const float v = in[((size_t)b * NN + idx) * CC + lane];
    out[(size_t)row * CC + lane] = v;
}

extern "C" void kernel_launch(void* const* d_in, const int* in_sizes, int n_in,
                              void* d_out, int out_size, void* d_ws, size_t ws_size,
                              hipStream_t stream) {
    const float* in = (const float*)d_in[0];
    float* out = (float*)d_out;

    const size_t ws_need = (size_t)BB * NN * 3 * sizeof(float);   // 6 MB
    if (ws_size >= ws_need) {
        float* cpts = (float*)d_ws;
        compact_kernel<<<(BB * NN) / 256, 256, 0, stream>>>(in, cpts);
        fps_kernel<<<BB, T, 0, stream>>>(out, cpts, 3, cpts, 3);
    } else {
        fps_kernel<<<BB, T, 0, stream>>>(out, in, CC, in, CC);
    }

    const int total = BB * NC * CC;          // 8,388,608
    gather_kernel<<<total / 256, 256, 0, stream>>>(in, out);
}